// Round 1
// baseline (648.991 us; speedup 1.0000x reference)
//
#include <hip/hip_runtime.h>
#include <math.h>

#define NN 8192
#define DD 128
#define MARGIN_F 1.0f

// ---------------- row squared-norms: one wave per row ----------------
__global__ __launch_bounds__(256) void norms_kernel(const float* __restrict__ x,
                                                    float* __restrict__ out) {
    int lane = threadIdx.x & 63;
    int row  = blockIdx.x * 4 + (threadIdx.x >> 6);
    const float2 v = *(const float2*)(x + (size_t)row * DD + lane * 2);
    float s = v.x * v.x + v.y * v.y;
#pragma unroll
    for (int off = 32; off >= 1; off >>= 1)
        s += __shfl_xor(s, off, 64);
    if (lane == 0) out[row] = s;
}

// ---------------- main distance pass ----------------
// PASS 0: row/col packed (value,index) mins.  PASS 1: hinge sums.
template <int PASS>
__global__ __launch_bounds__(256) void dist_pass(
    const float* __restrict__ A, const float* __restrict__ B,
    const float* __restrict__ na, const float* __restrict__ nb,
    unsigned long long* __restrict__ rowpack,
    unsigned long long* __restrict__ colpack,
    float* __restrict__ sumR, float* __restrict__ sumC) {
    __shared__ float As[64][132];
    __shared__ float Bs[64][132];

    const int tid = threadIdx.x;
    const int tx = tid & 15;   // col group 0..15
    const int ty = tid >> 4;   // row group 0..15
    const int rowBase = blockIdx.y * 64;
    const int colBase = blockIdx.x * 64;

    const float* aG = A + (size_t)rowBase * DD;
    const float* bG = B + (size_t)colBase * DD;
#pragma unroll
    for (int it = 0; it < 8; ++it) {
        int idx = tid + 256 * it;   // 0..2047
        int r = idx >> 5;           // row in tile (32 float4 per row)
        int c = (idx & 31) << 2;    // col (float index)
        *(float4*)&As[r][c] = *(const float4*)(aG + r * DD + c);
        *(float4*)&Bs[r][c] = *(const float4*)(bG + r * DD + c);
    }
    __syncthreads();

    float acc[4][4];
#pragma unroll
    for (int i = 0; i < 4; ++i)
#pragma unroll
        for (int j = 0; j < 4; ++j) acc[i][j] = 0.f;

#pragma unroll 4
    for (int k4 = 0; k4 < 32; ++k4) {
        float4 av[4], bv[4];
#pragma unroll
        for (int ri = 0; ri < 4; ++ri) av[ri] = *(const float4*)&As[ty + 16 * ri][k4 * 4];
#pragma unroll
        for (int ci = 0; ci < 4; ++ci) bv[ci] = *(const float4*)&Bs[tx + 16 * ci][k4 * 4];
#pragma unroll
        for (int ri = 0; ri < 4; ++ri)
#pragma unroll
            for (int ci = 0; ci < 4; ++ci) {
                float a0 = acc[ri][ci];
                a0 = fmaf(av[ri].x, bv[ci].x, a0);
                a0 = fmaf(av[ri].y, bv[ci].y, a0);
                a0 = fmaf(av[ri].z, bv[ci].z, a0);
                a0 = fmaf(av[ri].w, bv[ci].w, a0);
                acc[ri][ci] = a0;
            }
    }

    float nar[4], nbc[4];
#pragma unroll
    for (int ri = 0; ri < 4; ++ri) nar[ri] = na[rowBase + ty + 16 * ri];
#pragma unroll
    for (int ci = 0; ci < 4; ++ci) nbc[ci] = nb[colBase + tx + 16 * ci];

    float dmat[4][4];
#pragma unroll
    for (int ri = 0; ri < 4; ++ri)
#pragma unroll
        for (int ci = 0; ci < 4; ++ci) {
            float sq = nar[ri] + nbc[ci] - 2.0f * acc[ri][ci];
            dmat[ri][ci] = sqrtf(fmaxf(sq, 0.0f));
        }

    if (PASS == 0) {
        unsigned long long rp[4], cp[4];
#pragma unroll
        for (int ri = 0; ri < 4; ++ri) {
            rp[ri] = ~0ull;
#pragma unroll
            for (int ci = 0; ci < 4; ++ci) {
                unsigned long long p =
                    ((unsigned long long)__float_as_uint(dmat[ri][ci]) << 32) |
                    (unsigned)(colBase + tx + 16 * ci);
                rp[ri] = rp[ri] < p ? rp[ri] : p;
            }
        }
#pragma unroll
        for (int ci = 0; ci < 4; ++ci) {
            cp[ci] = ~0ull;
#pragma unroll
            for (int ri = 0; ri < 4; ++ri) {
                unsigned long long p =
                    ((unsigned long long)__float_as_uint(dmat[ri][ci]) << 32) |
                    (unsigned)(rowBase + ty + 16 * ri);
                cp[ci] = cp[ci] < p ? cp[ci] : p;
            }
        }
        __syncthreads();
        unsigned long long* red = (unsigned long long*)&As[0][0];  // [16][64] x2
#pragma unroll
        for (int ri = 0; ri < 4; ++ri) red[tx * 64 + ty + 16 * ri] = rp[ri];
#pragma unroll
        for (int ci = 0; ci < 4; ++ci) red[1024 + ty * 64 + tx + 16 * ci] = cp[ci];
        __syncthreads();
        if (tid < 64) {
            unsigned long long m = ~0ull;
#pragma unroll
            for (int t = 0; t < 16; ++t) {
                unsigned long long v = red[t * 64 + tid];
                m = m < v ? m : v;
            }
            atomicMin(&rowpack[rowBase + tid], m);
        } else if (tid < 128) {
            int c = tid - 64;
            unsigned long long m = ~0ull;
#pragma unroll
            for (int t = 0; t < 16; ++t) {
                unsigned long long v = red[1024 + t * 64 + c];
                m = m < v ? m : v;
            }
            atomicMin(&colpack[colBase + c], m);
        }
    } else {
        float posR[4], posC[4];
        int jm[4], im[4];
#pragma unroll
        for (int ri = 0; ri < 4; ++ri) {
            unsigned long long p = rowpack[rowBase + ty + 16 * ri];
            posR[ri] = __uint_as_float((unsigned)(p >> 32));
            jm[ri] = (int)(unsigned)(p & 0xFFFFFFFFull);
        }
#pragma unroll
        for (int ci = 0; ci < 4; ++ci) {
            unsigned long long p = colpack[colBase + tx + 16 * ci];
            posC[ci] = __uint_as_float((unsigned)(p >> 32));
            im[ci] = (int)(unsigned)(p & 0xFFFFFFFFull);
        }
        float rs[4] = {0.f, 0.f, 0.f, 0.f};
        float cs[4] = {0.f, 0.f, 0.f, 0.f};
#pragma unroll
        for (int ri = 0; ri < 4; ++ri)
#pragma unroll
            for (int ci = 0; ci < 4; ++ci) {
                int row = rowBase + ty + 16 * ri;
                int col = colBase + tx + 16 * ci;
                float d = dmat[ri][ci];
                float hr = fmaxf(0.0f, MARGIN_F - posR[ri] + d);
                if (col != jm[ri]) rs[ri] += hr;
                float hc = fmaxf(0.0f, MARGIN_F - posC[ci] + d);
                if (row != im[ci]) cs[ci] += hc;
            }
        __syncthreads();
        float* red = (float*)&As[0][0];  // [16][64] x2
#pragma unroll
        for (int ri = 0; ri < 4; ++ri) red[tx * 64 + ty + 16 * ri] = rs[ri];
#pragma unroll
        for (int ci = 0; ci < 4; ++ci) red[1024 + ty * 64 + tx + 16 * ci] = cs[ci];
        __syncthreads();
        if (tid < 64) {
            float s = 0.f;
#pragma unroll
            for (int t = 0; t < 16; ++t) s += red[t * 64 + tid];
            atomicAdd(&sumR[rowBase + tid], s);
        } else if (tid < 128) {
            int c = tid - 64;
            float s = 0.f;
#pragma unroll
            for (int t = 0; t < 16; ++t) s += red[1024 + t * 64 + c];
            atomicAdd(&sumC[colBase + c], s);
        }
    }
}

// ---------------- final scalar reduce ----------------
__global__ __launch_bounds__(256) void finalize_kernel(const float* __restrict__ sumR,
                                                       const float* __restrict__ sumC,
                                                       float* __restrict__ out) {
    float s = 0.f;
    for (int i = threadIdx.x; i < NN; i += 256) s += sumR[i] + sumC[i];
    __shared__ float red[4];
#pragma unroll
    for (int off = 32; off >= 1; off >>= 1) s += __shfl_xor(s, off, 64);
    int lane = threadIdx.x & 63, wave = threadIdx.x >> 6;
    if (lane == 0) red[wave] = s;
    __syncthreads();
    if (threadIdx.x == 0) {
        float t = red[0] + red[1] + red[2] + red[3];
        // * 0.5 / (N*M)
        out[0] = t * (0.5f / (8192.0f * 8192.0f));
    }
}

extern "C" void kernel_launch(void* const* d_in, const int* in_sizes, int n_in,
                              void* d_out, int out_size, void* d_ws, size_t ws_size,
                              hipStream_t stream) {
    const float* A = (const float*)d_in[0];
    const float* B = (const float*)d_in[1];
    char* ws = (char*)d_ws;

    unsigned long long* rowpack = (unsigned long long*)(ws);            // 64 KB
    unsigned long long* colpack = (unsigned long long*)(ws + 65536);    // 64 KB
    float* sumR = (float*)(ws + 131072);                                // 32 KB
    float* sumC = (float*)(ws + 131072 + 32768);                        // 32 KB
    float* na   = (float*)(ws + 196608);                                // 32 KB
    float* nb   = (float*)(ws + 196608 + 32768);                        // 32 KB

    hipMemsetAsync(rowpack, 0xFF, 131072, stream);  // u64 max for min-reduction
    hipMemsetAsync(sumR, 0, 65536, stream);         // zero both sum arrays

    norms_kernel<<<NN / 4, 256, 0, stream>>>(A, na);
    norms_kernel<<<NN / 4, 256, 0, stream>>>(B, nb);

    dim3 grid(NN / 64, NN / 64);
    dist_pass<0><<<grid, 256, 0, stream>>>(A, B, na, nb, rowpack, colpack, sumR, sumC);
    dist_pass<1><<<grid, 256, 0, stream>>>(A, B, na, nb, rowpack, colpack, sumR, sumC);

    finalize_kernel<<<1, 256, 0, stream>>>(sumR, sumC, (float*)d_out);
}

// Round 2
// 157.730 us; speedup vs baseline: 4.1146x; 4.1146x over previous
//
#include <hip/hip_runtime.h>
#include <hip/hip_bf16.h>
#include <math.h>

#define NN 8192
#define DD 128
#define MARGIN_F 1.0f
#define BIGF 3.402823466e+38f

typedef __attribute__((ext_vector_type(8))) short short8;
typedef __attribute__((ext_vector_type(4))) float f32x4;

// ---------------- prep: fp32 -> bf16 convert + exact fp32 row norms ----------------
__global__ __launch_bounds__(256) void prep_kernel(const float* __restrict__ x,
                                                   __hip_bfloat16* __restrict__ xb,
                                                   float* __restrict__ norm) {
    int lane = threadIdx.x & 63;
    int row  = blockIdx.x * 4 + (threadIdx.x >> 6);
    const float2 v = *(const float2*)(x + (size_t)row * DD + lane * 2);
    float s = v.x * v.x + v.y * v.y;
    __hip_bfloat162 h;
    h.x = __float2bfloat16(v.x);
    h.y = __float2bfloat16(v.y);
    *(__hip_bfloat162*)(xb + (size_t)row * DD + lane * 2) = h;
#pragma unroll
    for (int off = 32; off >= 1; off >>= 1) s += __shfl_xor(s, off, 64);
    if (lane == 0) norm[row] = s;
}

// ---------------- main MFMA distance pass ----------------
// 128x128 tile per block, 4 waves (2x2), each wave 64x64 = 4x4 frags of 16x16x32.
// PASS 0: u32-bit min of d^2 per row/col.  PASS 1: hinge sums (exclude d2==min).
template <int PASS>
__global__ __launch_bounds__(256, 2) void dist_mfma(
    const __hip_bfloat16* __restrict__ Ab, const __hip_bfloat16* __restrict__ Bb,
    const float* __restrict__ na, const float* __restrict__ nb,
    unsigned int* __restrict__ rowmin, unsigned int* __restrict__ colmin,
    const float* __restrict__ rowp1m, const float* __restrict__ colp1m,
    float* __restrict__ partial) {
    __shared__ char lds[65536];
    char* ldsA = lds;
    char* ldsB = lds + 32768;
    const int tid = threadIdx.x;
    const int rowBase = blockIdx.y * 128;
    const int colBase = blockIdx.x * 128;

    // ---- stage both 128x128 bf16 tiles into LDS with 16B-slot XOR swizzle ----
    const unsigned short* aG = (const unsigned short*)Ab + (size_t)rowBase * DD;
    const unsigned short* bG = (const unsigned short*)Bb + (size_t)colBase * DD;
#pragma unroll
    for (int it = 0; it < 8; ++it) {
        int idx = tid + 256 * it;      // 0..2047
        int r = idx >> 4;              // tile row 0..127
        int c16 = idx & 15;            // 16B chunk within row
        int dst = r * 256 + ((c16 * 16) ^ ((r & 7) << 4));
        *(short8*)(ldsA + dst) = *(const short8*)(aG + r * DD + c16 * 8);
        *(short8*)(ldsB + dst) = *(const short8*)(bG + r * DD + c16 * 8);
    }
    __syncthreads();

    const int l = tid & 63, wid = tid >> 6;
    const int wr = wid >> 1, wc = wid & 1;   // wave 64x64 sub-tile
    const int g = l >> 4, c = l & 15;

    f32x4 acc[4][4];
#pragma unroll
    for (int mi = 0; mi < 4; ++mi)
#pragma unroll
        for (int ni = 0; ni < 4; ++ni) acc[mi][ni] = (f32x4)0.f;

#pragma unroll
    for (int kk = 0; kk < 4; ++kk) {
        short8 af[4], bf[4];
        const int kbyte = kk * 64 + g * 16;
#pragma unroll
        for (int mi = 0; mi < 4; ++mi) {
            int r = wr * 64 + mi * 16 + c;
            af[mi] = *(const short8*)(ldsA + r * 256 + (kbyte ^ ((r & 7) << 4)));
            int r2 = wc * 64 + mi * 16 + c;
            bf[mi] = *(const short8*)(ldsB + r2 * 256 + (kbyte ^ ((r2 & 7) << 4)));
        }
#pragma unroll
        for (int mi = 0; mi < 4; ++mi)
#pragma unroll
            for (int ni = 0; ni < 4; ++ni)
                acc[mi][ni] = __builtin_amdgcn_mfma_f32_16x16x32_bf16(
                    af[mi], bf[ni], acc[mi][ni], 0, 0, 0);
    }

    // out_row = row0 + mi*16 + g*4 + reg ; out_col = col0 + ni*16 + c
    const int row0 = rowBase + wr * 64;
    const int col0 = colBase + wc * 64;

    if (PASS == 0) {
        float nbc[4];
#pragma unroll
        for (int ni = 0; ni < 4; ++ni) nbc[ni] = nb[col0 + ni * 16 + c];
        float colm[4] = {BIGF, BIGF, BIGF, BIGF};
#pragma unroll
        for (int mi = 0; mi < 4; ++mi) {
            const f32x4 na4 = *(const f32x4*)(na + row0 + mi * 16 + g * 4);
            float rowm[4] = {BIGF, BIGF, BIGF, BIGF};
#pragma unroll
            for (int ni = 0; ni < 4; ++ni) {
                f32x4 a = acc[mi][ni];
#pragma unroll
                for (int reg = 0; reg < 4; ++reg) {
                    float d2 = fmaf(-2.0f, a[reg], na4[reg] + nbc[ni]);
                    rowm[reg] = fminf(rowm[reg], d2);
                    colm[ni] = fminf(colm[ni], d2);
                }
            }
#pragma unroll
            for (int reg = 0; reg < 4; ++reg) {
                float m = rowm[reg];
                m = fminf(m, __shfl_xor(m, 1, 64));
                m = fminf(m, __shfl_xor(m, 2, 64));
                m = fminf(m, __shfl_xor(m, 4, 64));
                m = fminf(m, __shfl_xor(m, 8, 64));
                rowm[reg] = m;
            }
            if (c == 0) {
#pragma unroll
                for (int reg = 0; reg < 4; ++reg)
                    atomicMin(&rowmin[row0 + mi * 16 + g * 4 + reg],
                              __float_as_uint(rowm[reg]));
            }
        }
#pragma unroll
        for (int ni = 0; ni < 4; ++ni) {
            float m = colm[ni];
            m = fminf(m, __shfl_xor(m, 16, 64));
            m = fminf(m, __shfl_xor(m, 32, 64));
            if (g == 0) atomicMin(&colmin[col0 + ni * 16 + c], __float_as_uint(m));
        }
    } else {
        float nbc[4], cminv[4], cp1[4];
        const float* colminf = (const float*)colmin;
#pragma unroll
        for (int ni = 0; ni < 4; ++ni) {
            int col = col0 + ni * 16 + c;
            nbc[ni] = nb[col];
            cminv[ni] = colminf[col];
            cp1[ni] = colp1m[col];
        }
        const float* rowminf = (const float*)rowmin;
        float tot = 0.f;
#pragma unroll
        for (int mi = 0; mi < 4; ++mi) {
            const int rbase = row0 + mi * 16 + g * 4;
            const f32x4 na4  = *(const f32x4*)(na + rbase);
            const f32x4 rmin = *(const f32x4*)(rowminf + rbase);
            const f32x4 rp1  = *(const f32x4*)(rowp1m + rbase);
#pragma unroll
            for (int ni = 0; ni < 4; ++ni) {
                f32x4 a = acc[mi][ni];
#pragma unroll
                for (int reg = 0; reg < 4; ++reg) {
                    float d2 = fmaf(-2.0f, a[reg], na4[reg] + nbc[ni]);
                    float d = sqrtf(fmaxf(d2, 0.f));
                    float hr = fmaxf(0.f, rp1[reg] + d);
                    if (d2 == rmin[reg]) hr = 0.f;
                    float hc = fmaxf(0.f, cp1[ni] + d);
                    if (d2 == cminv[ni]) hc = 0.f;
                    tot += hr + hc;
                }
            }
        }
#pragma unroll
        for (int off = 32; off >= 1; off >>= 1) tot += __shfl_xor(tot, off, 64);
        __syncthreads();   // everyone done reading LDS tiles
        float* red = (float*)lds;
        if (l == 0) red[wid] = tot;
        __syncthreads();
        if (tid == 0)
            atomicAdd(&partial[blockIdx.y], red[0] + red[1] + red[2] + red[3]);
    }
}

// ---------------- mid: pos helpers (1 - sqrt(min d^2)) for rows & cols ----------------
__global__ __launch_bounds__(256) void mid_kernel(const unsigned int* __restrict__ minbits,
                                                  float* __restrict__ p1m) {
    int i = blockIdx.x * 256 + threadIdx.x;   // 16384 = rows then cols
    float m = __uint_as_float(minbits[i]);
    p1m[i] = MARGIN_F - sqrtf(fmaxf(m, 0.f));
}

// ---------------- final scalar ----------------
__global__ __launch_bounds__(64) void final_kernel(const float* __restrict__ partial,
                                                   float* __restrict__ out) {
    float s = partial[threadIdx.x];   // 64 partials
#pragma unroll
    for (int off = 32; off >= 1; off >>= 1) s += __shfl_xor(s, off, 64);
    if (threadIdx.x == 0)
        out[0] = s * (0.5f / (8192.0f * 8192.0f));
}

extern "C" void kernel_launch(void* const* d_in, const int* in_sizes, int n_in,
                              void* d_out, int out_size, void* d_ws, size_t ws_size,
                              hipStream_t stream) {
    const float* A = (const float*)d_in[0];
    const float* B = (const float*)d_in[1];
    char* ws = (char*)d_ws;

    const size_t MB = 1024 * 1024;
    __hip_bfloat16* Abf = (__hip_bfloat16*)(ws);                 // 2 MB
    __hip_bfloat16* Bbf = (__hip_bfloat16*)(ws + 2 * MB);        // 2 MB
    float* na            = (float*)(ws + 4 * MB);                // 32 KB
    float* nb            = (float*)(ws + 4 * MB + 32768);        // 32 KB
    unsigned int* rowmin = (unsigned int*)(ws + 4 * MB + 65536); // 32 KB
    unsigned int* colmin = (unsigned int*)(ws + 4 * MB + 98304); // 32 KB (contig after rowmin)
    float* rowp1m        = (float*)(ws + 4 * MB + 131072);       // 32 KB
    float* colp1m        = (float*)(ws + 4 * MB + 163840);       // 32 KB (contig after rowp1m)
    float* partial       = (float*)(ws + 4 * MB + 196608);       // 256 B

    hipMemsetAsync(rowmin, 0xFF, 65536, stream);   // rowmin+colmin -> u32 max
    hipMemsetAsync(partial, 0, 256, stream);

    prep_kernel<<<NN / 4, 256, 0, stream>>>(A, Abf, na);
    prep_kernel<<<NN / 4, 256, 0, stream>>>(B, Bbf, nb);

    dim3 grid(NN / 128, NN / 128);
    dist_mfma<0><<<grid, 256, 0, stream>>>(Abf, Bbf, na, nb, rowmin, colmin,
                                           nullptr, nullptr, nullptr);
    mid_kernel<<<16384 / 256, 256, 0, stream>>>(rowmin, rowp1m);
    dist_mfma<1><<<grid, 256, 0, stream>>>(Abf, Bbf, na, nb, rowmin, colmin,
                                           rowp1m, colp1m, partial);
    final_kernel<<<1, 64, 0, stream>>>(partial, (float*)d_out);
}